// Round 3
// baseline (43.223 us; speedup 1.0000x reference)
//
#include <hip/hip_runtime.h>
#include <math.h>

// Problem constants (from reference)
constexpr int Bb = 8, Cc = 16, Hh = 96, Ww = 96;
constexpr int Ho = 94, Wo = 94;          // VALID 3x3
constexpr int NC = 4;                    // n_convs
constexpr int PLANE = Ho * Wo;           // 8836

// Tiling
constexpr int TX = 32, TY = 16;          // output tile per block
constexpr int IX = TX + 2, IY = TY + 2;  // 34 x 18 input/feature tile
constexpr int NXT = 3;                   // ceil(94/32)
constexpr int NYT = 6;                   // ceil(94/16)
constexpr int FS = 12;                   // floats per pixel feature record

__global__ __launch_bounds__(256)
void kan_conv_kernel(const float* __restrict__ x,
                     const float* __restrict__ base_w,        // (4,9)
                     const float* __restrict__ spline_w,      // (4,9,8)
                     const float* __restrict__ spline_scaler, // (4,9)
                     const float* __restrict__ grid,          // (12)
                     float* __restrict__ out)                 // (8,64,94,94)
{
    __shared__ float feat[IY][IX][FS];

    const int tid = threadIdx.x;
    int blk = blockIdx.x;
    const int xt = blk % NXT; blk /= NXT;
    const int yt = blk % NYT; blk /= NYT;
    const int c  = blk % Cc;
    const int b  = blk / Cc;
    const int ox0 = xt * TX, oy0 = yt * TY;

    const float g0   = grid[0];
    const float invh = 1.0f / (grid[1] - g0);

    const float* xplane = x + (size_t)(b * Cc + c) * Hh * Ww;

    // ---------- Phase 1: per-pixel features (silu + 8 cubic B-spline bases) ----------
    for (int p = tid; p < IX * IY; p += 256) {
        const int py = p / IX, px = p % IX;
        const int gy = oy0 + py, gx = ox0 + px;
        const float v = (gy < Hh && gx < Ww) ? xplane[gy * Ww + gx] : 0.0f;

        const float sl = v / (1.0f + __expf(-v));   // silu

        // Uniform-grid cubic B-spline: interval j, local coord t in [0,1)
        const float u = (v - g0) * invh;
        int j = (int)u;                              // floor for u>=0
        if (!(u >= 0.0f && u < 11.0f)) j = -100;     // outside grid -> all bases zero
        const float t  = u - (float)j;
        const float t2 = t * t, t3 = t2 * t;
        const float omt = 1.0f - t;
        const float B0 = (1.0f / 6.0f) * omt * omt * omt;                    // idx j-3
        const float B1 = (1.0f / 6.0f) * (3.0f * t3 - 6.0f * t2 + 4.0f);     // j-2
        const float B2 = (1.0f / 6.0f) * (-3.0f * t3 + 3.0f * t2 + 3.0f * t + 1.0f); // j-1
        const float B3 = (1.0f / 6.0f) * t3;                                 // j

        float bb[8];
#pragma unroll
        for (int k = 0; k < 8; ++k) {
            float r = 0.0f;
            r = (j == k + 3) ? B0 : r;
            r = (j == k + 2) ? B1 : r;
            r = (j == k + 1) ? B2 : r;
            r = (j == k    ) ? B3 : r;
            bb[k] = r;
        }

        float4* fp = (float4*)&feat[py][px][0];
        fp[0] = make_float4(sl,    bb[0], bb[1], bb[2]);
        fp[1] = make_float4(bb[3], bb[4], bb[5], bb[6]);
        fp[2] = make_float4(bb[7], 0.0f,  0.0f,  0.0f);
    }

    __syncthreads();

    // ---------- Phase 2: load ALL features for this thread's 2 outputs into regs ----------
    const int tx = tid & 31;        // 0..31 -> output col ox0+tx
    const int ty = tid >> 5;        // 0..7  -> output rows 2ty, 2ty+1
    const int ox = ox0 + tx;

    float4 qa[4][3];                // [input row 2ty+rr][px dx]: silu, b0, b1, b2
    float4 qb[4][3];                // b3..b6
    float  qc[4][3];                // b7
#pragma unroll
    for (int rr = 0; rr < 4; ++rr) {
#pragma unroll
        for (int px = 0; px < 3; ++px) {
            const float* fp = &feat[2 * ty + rr][tx + px][0];
            qa[rr][px] = *(const float4*)fp;
            qb[rr][px] = *(const float4*)(fp + 4);
            qc[rr][px] = fp[8];
        }
    }
    // Keep the pure-SMEM weight stream below from being interleaved with the
    // DS reads above (both share lgkmcnt -> mixed waits serialize everything).
    __builtin_amdgcn_sched_barrier(0);

    // ---------- Phase 3: weight application — only s_load + v_fma ----------
    float acc[2][4] = {{0.f, 0.f, 0.f, 0.f}, {0.f, 0.f, 0.f, 0.f}};

#pragma unroll
    for (int dy = 0; dy < 3; ++dy) {
#pragma unroll
        for (int dx = 0; dx < 3; ++dx) {
            const int i = dy * 3 + dx;
#pragma unroll
            for (int cv = 0; cv < 4; ++cv) {
                const int wi = cv * 9 + i;
                const float bw = base_w[wi];
                const float sc = spline_scaler[wi];
                const float* sw = &spline_w[wi * 8];
#pragma unroll
                for (int r = 0; r < 2; ++r) {
                    const int rr = dy + r;           // compile-time after unroll
                    const float4 a = qa[rr][dx];
                    const float4 bvec = qb[rr][dx];
                    float dot = a.y * sw[0];
                    dot = fmaf(a.z,        sw[1], dot);
                    dot = fmaf(a.w,        sw[2], dot);
                    dot = fmaf(bvec.x,     sw[3], dot);
                    dot = fmaf(bvec.y,     sw[4], dot);
                    dot = fmaf(bvec.z,     sw[5], dot);
                    dot = fmaf(bvec.w,     sw[6], dot);
                    dot = fmaf(qc[rr][dx], sw[7], dot);
                    acc[r][cv] = fmaf(a.x, bw, fmaf(sc, dot, acc[r][cv]));
                }
            }
        }
    }

    // ---------- Stores: 4 conv planes, coalesced ----------
    float* obase = out + (size_t)((b * Cc + c) * NC) * PLANE;
#pragma unroll
    for (int r = 0; r < 2; ++r) {
        const int oy = oy0 + 2 * ty + r;
        if (ox < Wo && oy < Ho) {
            float* op = obase + oy * Wo + ox;
            op[0 * PLANE] = acc[r][0];
            op[1 * PLANE] = acc[r][1];
            op[2 * PLANE] = acc[r][2];
            op[3 * PLANE] = acc[r][3];
        }
    }
}

extern "C" void kernel_launch(void* const* d_in, const int* in_sizes, int n_in,
                              void* d_out, int out_size, void* d_ws, size_t ws_size,
                              hipStream_t stream) {
    const float* x             = (const float*)d_in[0];
    const float* base_w        = (const float*)d_in[1];
    const float* spline_w      = (const float*)d_in[2];
    const float* spline_scaler = (const float*)d_in[3];
    const float* grid          = (const float*)d_in[4];
    float* out = (float*)d_out;

    const int nblocks = Bb * Cc * NYT * NXT;  // 8*16*6*3 = 2304
    kan_conv_kernel<<<nblocks, 256, 0, stream>>>(x, base_w, spline_w,
                                                 spline_scaler, grid, out);
}